// Round 4
// baseline (2918.576 us; speedup 1.0000x reference)
//
#include <hip/hip_runtime.h>
#include <cstdint>
#include <cstddef>

#define NTR 16384
#define NQR 4096
#define NROW 20480
#define DF  128
#define NCL 19

// ---- workspace layout (bytes) ----
#define OFF_RN    (size_t)0                  // float[20480] (train rows 0..16383, query rows 16384..20479)
#define OFF_SNBR  (size_t)81920              // int[20480][4][20]
#define OFF_SD    (size_t)6635520            // float[20480][4][20]
#define OFF_NBRT  (size_t)13189120           // int[16384][20]
#define OFF_NBRQ  (size_t)14499840           // int[4096][20]
#define OFF_HIST  (size_t)14827520           // int[2][2][19][32]
#define OFF_COND  (size_t)14837248           // float[2][2][19][32]
#define OFF_PRIOR (size_t)14846976           // float[19]
#define WS_NEEDED (size_t)14847056

// separately-rounded multiply (asm barrier blocks mul+add -> fma contraction)
__device__ __forceinline__ float mulr(float a, float b) {
  float m = a * b;
  asm volatile("" : "+v"(m));
  return m;
}

// ---------------- row norms: strict ascending scalar sum of separately-rounded
// squares (XLA-CPU-style minor-dim reduce, no FMA, no reassociation) ----------
__global__ __launch_bounds__(256) void norms_kernel(const float* __restrict__ train,
                                                    const float* __restrict__ feat,
                                                    float* __restrict__ rn) {
  int i = blockIdx.x * 256 + threadIdx.x;  // 80 blocks -> 20480
  const float* src = (i < NTR) ? (train + (size_t)i * DF) : (feat + (size_t)(i - NTR) * DF);
  float s = 0.0f;
  for (int k = 0; k < DF; ++k) {
    float x = src[k];
    s = s + mulr(x, x);
  }
  rn[i] = s;
}

// ---------------- sorted top-20 insertion (registers only, fully static) -----
__device__ __forceinline__ void insert20(float (&sd)[20], int (&si)[20], float d, int idx) {
#pragma unroll
  for (int j = 19; j >= 1; --j) {
    bool w = sd[j] > d;       // position j changes at all
    bool c = sd[j - 1] > d;   // element j-1 shifts into j
    if (w) {
      sd[j] = c ? sd[j - 1] : d;
      si[j] = c ? si[j - 1] : idx;
    }
  }
  if (sd[0] > d) { sd[0] = d; si[0] = idx; }
}

// ---------------- fused f32 distance-GEMM + per-slice top-20 ----------------
// Block: 256 threads. 64 rows x 4096-candidate slice, tiles of 64 cands.
// d = (na + nb) - 2*ab with ab = ascending-k chain of separately-rounded
// mul then add (Eigen-without-FMA realization).
__global__ __launch_bounds__(256, 2) void knn_kernel(const float* __restrict__ train,
                                                     const float* __restrict__ feat,
                                                     const float* __restrict__ rn,
                                                     int* __restrict__ snbr,
                                                     float* __restrict__ sdist) {
  constexpr int ATS = 132, BTS = 68, DTS = 65;
  constexpr size_t AT_BYTES = (size_t)64 * ATS * 4;   // 33792
  constexpr size_t BT_BYTES = (size_t)64 * BTS * 4;   // 17408
  constexpr size_t DT_BYTES = (size_t)64 * DTS * 4;   // 16640
  constexpr size_t MD_BYTES = (size_t)64 * 4 * 20 * 4;
  constexpr size_t PH1 = AT_BYTES + BT_BYTES + DT_BYTES;     // 67840
  constexpr size_t PH2 = MD_BYTES * 2;                       // 40960
  constexpr size_t SMEM = PH1 > PH2 ? PH1 : PH2;
  __shared__ __align__(16) char smem[SMEM];
  float (*At)[ATS] = reinterpret_cast<float (*)[ATS]>(smem);
  float (*Bt)[BTS] = reinterpret_cast<float (*)[BTS]>(smem + AT_BYTES);
  float (*Dt)[DTS] = reinterpret_cast<float (*)[DTS]>(smem + AT_BYTES + BT_BYTES);

  const int b = blockIdx.x;            // 1280 blocks
  const int rowblock = b >> 2, slice = b & 3;
  const int grow0 = rowblock * 64;     // global row id (train rows then query rows)
  const float* rows_feat = (rowblock < 256)
      ? (train + (size_t)grow0 * DF)
      : (feat + (size_t)(grow0 - NTR) * DF);

  const int tid = threadIdx.x;
  const int tx = tid & 15, ty = tid >> 4;  // micro-tile: rows ty*4.., cands tx*4..

  // stage the 64-row A block (reused across all candidate tiles)
  for (int u = tid; u < 64 * 32; u += 256) {
    int r = u >> 5, k4 = (u & 31) << 2;
    *reinterpret_cast<float4*>(&At[r][k4]) =
        *reinterpret_cast<const float4*>(rows_feat + (size_t)r * DF + k4);
  }

  float na_r[4];
#pragma unroll
  for (int i = 0; i < 4; ++i) na_r[i] = rn[grow0 + ty * 4 + i];

  float sd[20];
  int si[20];
#pragma unroll
  for (int t = 0; t < 20; ++t) { sd[t] = 3.0e38f; si[t] = 0x7fffffff; }
  const int selrow = tid & 63, selseg = tid >> 6;  // 4 segments of 16 cands/tile
  const int cbase0 = slice * 4096;

  for (int nt0 = 0; nt0 < 4096; nt0 += 64) {
    float acc[4][4];
#pragma unroll
    for (int i = 0; i < 4; ++i)
#pragma unroll
      for (int j = 0; j < 4; ++j) acc[i][j] = 0.0f;

#pragma unroll
    for (int kc = 0; kc < 2; ++kc) {
      __syncthreads();  // prev compute done with Bt; (kc==0) prev selection done with Dt
      for (int u = tid; u < 64 * 16; u += 256) {
        int c = u >> 4, kk = (u & 15) << 2;
        *reinterpret_cast<float4*>(&Bt[c][kk]) =
            *reinterpret_cast<const float4*>(train + (size_t)(cbase0 + nt0 + c) * DF + kc * 64 + kk);
      }
      __syncthreads();
#pragma unroll 2
      for (int k = 0; k < 64; k += 4) {
        float4 af[4], bf[4];
#pragma unroll
        for (int i = 0; i < 4; ++i)
          af[i] = *reinterpret_cast<const float4*>(&At[ty * 4 + i][kc * 64 + k]);
#pragma unroll
        for (int j = 0; j < 4; ++j)
          bf[j] = *reinterpret_cast<const float4*>(&Bt[tx * 4 + j][k]);
        // ascending-k chain, separate mul/add rounding (no FMA) per accumulator
#pragma unroll
        for (int i = 0; i < 4; ++i)
#pragma unroll
          for (int j = 0; j < 4; ++j) {
            acc[i][j] = acc[i][j] + mulr(af[i].x, bf[j].x);
            acc[i][j] = acc[i][j] + mulr(af[i].y, bf[j].y);
            acc[i][j] = acc[i][j] + mulr(af[i].z, bf[j].z);
            acc[i][j] = acc[i][j] + mulr(af[i].w, bf[j].w);
          }
      }
    }
    // epilogue: d = (na+nb) - 2*ab  (2*ab exact; contraction of the sub is bit-identical)
#pragma unroll
    for (int j = 0; j < 4; ++j) {
      float nb_ = rn[cbase0 + nt0 + tx * 4 + j];
#pragma unroll
      for (int i = 0; i < 4; ++i) {
        float t1 = na_r[i] + nb_;
        Dt[ty * 4 + i][tx * 4 + j] = t1 - 2.0f * acc[i][j];
      }
    }
    __syncthreads();
    // selection: each thread scans 16 cands of its row (ascending index order)
    {
      int cb = selseg * 16;
      for (int c = 0; c < 16; ++c) {
        float d = Dt[selrow][cb + c];
        if (d < sd[19]) insert20(sd, si, d, cbase0 + nt0 + cb + c);
      }
    }
  }

  __syncthreads();  // all selection reads done; reuse smem for merge
  float* md = reinterpret_cast<float*>(smem);
  int* mi = reinterpret_cast<int*>(smem + MD_BYTES);
  {
    int bb = (selrow * 4 + selseg) * 20;
#pragma unroll
    for (int t = 0; t < 20; ++t) { md[bb + t] = sd[t]; mi[bb + t] = si[t]; }
  }
  __syncthreads();
  if (tid < 64) {
    const float* L0 = md + ((size_t)tid * 4 + 0) * 20; const int* I0 = mi + ((size_t)tid * 4 + 0) * 20;
    const float* L1 = md + ((size_t)tid * 4 + 1) * 20; const int* I1 = mi + ((size_t)tid * 4 + 1) * 20;
    const float* L2 = md + ((size_t)tid * 4 + 2) * 20; const int* I2 = mi + ((size_t)tid * 4 + 2) * 20;
    const float* L3 = md + ((size_t)tid * 4 + 3) * 20; const int* I3 = mi + ((size_t)tid * 4 + 3) * 20;
    int p0 = 0, p1 = 0, p2 = 0, p3 = 0;
    size_t obase = ((size_t)(grow0 + tid) * 4 + slice) * 20;
    for (int t = 0; t < 20; ++t) {
      float d0 = L0[p0], d1 = L1[p1], d2 = L2[p2], d3 = L3[p3];
      int j0 = I0[p0], j1 = I1[p1], j2 = I2[p2], j3 = I3[p3];
      bool c01 = d0 < d1 || (d0 == d1 && j0 < j1);
      float dA = c01 ? d0 : d1; int jA = c01 ? j0 : j1;
      bool c23 = d2 < d3 || (d2 == d3 && j2 < j3);
      float dB = c23 ? d2 : d3; int jB = c23 ? j2 : j3;
      bool cAB = dA < dB || (dA == dB && jA < jB);
      snbr[obase + t] = cAB ? jA : jB;
      sdist[obase + t] = cAB ? dA : dB;
      int win = cAB ? (c01 ? 0 : 1) : (c23 ? 2 : 3);
      p0 += (win == 0); p1 += (win == 1); p2 += (win == 2); p3 += (win == 3);
    }
  }
}

// ---------------- cross-slice 4-way merge -> final sorted top-20 ----------------
__global__ __launch_bounds__(256) void merge_kernel(const int* __restrict__ snbr,
                                                    const float* __restrict__ sdist,
                                                    int* __restrict__ nbrt,
                                                    int* __restrict__ nbrq) {
  int row = blockIdx.x * 256 + threadIdx.x;  // 80 blocks -> 20480
  int* outp = (row < NTR) ? (nbrt + (size_t)row * 20) : (nbrq + (size_t)(row - NTR) * 20);
  const float* D = sdist + (size_t)row * 80;
  const int* J = snbr + (size_t)row * 80;
  int p0 = 0, p1 = 20, p2 = 40, p3 = 60;
  for (int t = 0; t < 20; ++t) {
    float d0 = D[p0], d1 = D[p1], d2 = D[p2], d3 = D[p3];
    int j0 = J[p0], j1 = J[p1], j2 = J[p2], j3 = J[p3];
    bool c01 = d0 < d1 || (d0 == d1 && j0 < j1);
    float dA = c01 ? d0 : d1; int jA = c01 ? j0 : j1;
    bool c23 = d2 < d3 || (d2 == d3 && j2 < j3);
    float dB = c23 ? d2 : d3; int jB = c23 ? j2 : j3;
    bool cAB = dA < dB || (dA == dB && jA < jB);
    outp[t] = cAB ? jA : jB;
    int win = cAB ? (c01 ? 0 : 1) : (c23 ? 2 : 3);
    p0 += (win == 0); p1 += (win == 1); p2 += (win == 2); p3 += (win == 3);
  }
}

// ---------------- label-count histograms (k=10 and k=20) ----------------
// ghist idx = ((ki*2 + pos)*19 + c)*32 + delta
__global__ __launch_bounds__(256) void hist_kernel(const int* __restrict__ labels,
                                                   const int* __restrict__ nbrt,
                                                   int* __restrict__ ghist) {
  __shared__ int h[2432];
  int tid = threadIdx.x;
  for (int i = tid; i < 2432; i += 256) h[i] = 0;
  __syncthreads();
  int row = blockIdx.x * 256 + tid;  // 64 blocks -> 16384
  int nb[20];
#pragma unroll
  for (int j = 0; j < 20; ++j) nb[j] = nbrt[(size_t)row * 20 + j];
  int cnt[NCL];
#pragma unroll
  for (int c = 0; c < NCL; ++c) cnt[c] = 0;
#pragma unroll
  for (int j = 0; j < 10; ++j) {
    const int* lr = labels + (size_t)nb[j] * NCL;
#pragma unroll
    for (int c = 0; c < NCL; ++c) cnt[c] += lr[c];
  }
  const int* myl = labels + (size_t)row * NCL;
  int my[NCL];
#pragma unroll
  for (int c = 0; c < NCL; ++c) my[c] = myl[c];
#pragma unroll
  for (int c = 0; c < NCL; ++c)
    atomicAdd(&h[((0 * 2 + my[c]) * NCL + c) * 32 + cnt[c]], 1);
#pragma unroll
  for (int j = 10; j < 20; ++j) {
    const int* lr = labels + (size_t)nb[j] * NCL;
#pragma unroll
    for (int c = 0; c < NCL; ++c) cnt[c] += lr[c];
  }
#pragma unroll
  for (int c = 0; c < NCL; ++c)
    atomicAdd(&h[((1 * 2 + my[c]) * NCL + c) * 32 + cnt[c]], 1);
  __syncthreads();
  for (int i = tid; i < 2432; i += 256) {
    int v = h[i];
    if (v) atomicAdd(&ghist[i], v);
  }
}

// ---------------- conditional tables + priors ----------------
__global__ __launch_bounds__(256) void prep_kernel(const int* __restrict__ ghist,
                                                   float* __restrict__ cond,
                                                   float* __restrict__ prior) {
  __shared__ int cpos[NCL];
  int tid = threadIdx.x;
  if (tid < NCL) {
    int s = 0;
    for (int d = 0; d < 32; ++d) s += ghist[((0 * 2 + 1) * NCL + tid) * 32 + d];
    cpos[tid] = s;
    prior[tid] = (1.0f + (float)s) / (2.0f + (float)NTR);
  }
  __syncthreads();
  for (int i = tid; i < 2432; i += 256) {
    int cc = (i >> 5) % NCL;
    int pos = ((i >> 5) / NCL) & 1;
    int ki = i / (2 * NCL * 32);
    int k = ki ? 20 : 10;
    float num = 1.0f + (float)ghist[i];
    float den = (float)(k + 1) + (float)(pos ? cpos[cc] : (NTR - cpos[cc]));
    cond[i] = num / den;
  }
}

// ---------------- posterior output ----------------
__global__ __launch_bounds__(256) void out_kernel(const int* __restrict__ labels,
                                                  const int* __restrict__ nbrq,
                                                  const float* __restrict__ cond,
                                                  const float* __restrict__ prior,
                                                  float* __restrict__ out) {
  int q = blockIdx.x * 256 + threadIdx.x;  // 16 blocks -> 4096
  int nb[20];
#pragma unroll
  for (int j = 0; j < 20; ++j) nb[j] = nbrq[(size_t)q * 20 + j];
  int cnt[NCL], d10[NCL];
#pragma unroll
  for (int c = 0; c < NCL; ++c) cnt[c] = 0;
#pragma unroll
  for (int j = 0; j < 10; ++j) {
    const int* lr = labels + (size_t)nb[j] * NCL;
#pragma unroll
    for (int c = 0; c < NCL; ++c) cnt[c] += lr[c];
  }
#pragma unroll
  for (int c = 0; c < NCL; ++c) d10[c] = cnt[c];
#pragma unroll
  for (int j = 10; j < 20; ++j) {
    const int* lr = labels + (size_t)nb[j] * NCL;
#pragma unroll
    for (int c = 0; c < NCL; ++c) cnt[c] += lr[c];
  }
#pragma unroll
  for (int ki = 0; ki < 2; ++ki) {
#pragma unroll
    for (int c = 0; c < NCL; ++c) {
      int delta = ki ? cnt[c] : d10[c];
      float pr = prior[c];
      float pt = pr * cond[((ki * 2 + 1) * NCL + c) * 32 + delta];
      float pf = (1.0f - pr) * cond[((ki * 2 + 0) * NCL + c) * 32 + delta];
      out[((size_t)ki * NQR + q) * NCL + c] = pt / (pt + pf);
    }
  }
}

extern "C" void kernel_launch(void* const* d_in, const int* in_sizes, int n_in,
                              void* d_out, int out_size, void* d_ws, size_t ws_size,
                              hipStream_t stream) {
  const float* feat = (const float*)d_in[0];     // [4096,128]
  const float* train = (const float*)d_in[1];    // [16384,128]
  const int* labels = (const int*)d_in[2];       // [16384,19]
  float* out = (float*)d_out;                    // [2,4096,19]
  if (ws_size < WS_NEEDED) return;               // loud failure via poisoned output
  char* w = (char*)d_ws;
  float* rn = (float*)(w + OFF_RN);
  int* snbr = (int*)(w + OFF_SNBR);
  float* sdist = (float*)(w + OFF_SD);
  int* nbrt = (int*)(w + OFF_NBRT);
  int* nbrq = (int*)(w + OFF_NBRQ);
  int* ghist = (int*)(w + OFF_HIST);
  float* cond = (float*)(w + OFF_COND);
  float* prior = (float*)(w + OFF_PRIOR);

  hipMemsetAsync(ghist, 0, 2432 * 4, stream);
  norms_kernel<<<80, 256, 0, stream>>>(train, feat, rn);
  knn_kernel<<<1280, 256, 0, stream>>>(train, feat, rn, snbr, sdist);
  merge_kernel<<<80, 256, 0, stream>>>(snbr, sdist, nbrt, nbrq);
  hist_kernel<<<64, 256, 0, stream>>>(labels, nbrt, ghist);
  prep_kernel<<<1, 256, 0, stream>>>(ghist, cond, prior);
  out_kernel<<<16, 256, 0, stream>>>(labels, nbrq, cond, prior, out);
}